// Round 1
// baseline (5783.866 us; speedup 1.0000x reference)
//
#include <hip/hip_runtime.h>
#include <math.h>

// Problem constants (from reference): B=8, T=2048, P=4, D=768
constexpr int kB = 8;
constexpr int kT = 2048;
constexpr int kD = 768;              // 768 = 192 float4 = 3 float4/lane per row
constexpr int ROWS_PER_WAVE = 4;
constexpr int WAVES_PER_BLOCK = 4;   // 256 threads
constexpr int ROWS_PER_BLOCK = ROWS_PER_WAVE * WAVES_PER_BLOCK; // 16

// out[b,i,0:768]   = (mask_i!=0) ? sum_{j<=i, mask_j!=0} softmax_j(x_i.x_j/sqrt(768)) * x_j : 0
//   NOTE: softmax denominator is over ALL j<=i (mask applied AFTER softmax, no renorm).
// out[b,i,768:1536] = x[b,i]
__global__ __launch_bounds__(256) void attn_fused(
    const float* __restrict__ x,     // [B,T,D]
    const float* __restrict__ mask,  // [B,T]
    float* __restrict__ out)         // [B,T,2D]
{
  const int lane = threadIdx.x & 63;
  const int wave = threadIdx.x >> 6;
  const int rowBase = blockIdx.x * ROWS_PER_BLOCK + wave * ROWS_PER_WAVE;
  const int b  = rowBase / kT;
  const int i0 = rowBase - b * kT;          // rows i0 .. i0+3, all in batch b
  const float* xb   = x + (size_t)b * kT * kD;
  const float* mrow = mask + (size_t)b * kT;

  // Register layout: element e = 256*k + 4*lane + c  (k in 0..2, c in 0..3)
  float4 q[ROWS_PER_WAVE][3];
#pragma unroll
  for (int r = 0; r < ROWS_PER_WAVE; ++r) {
    const float4* xi = (const float4*)(xb + (size_t)(i0 + r) * kD);
#pragma unroll
    for (int k = 0; k < 3; ++k) q[r][k] = xi[k * 64 + lane];
  }

  float4 o[ROWS_PER_WAVE][3];
  float m[ROWS_PER_WAVE], l[ROWS_PER_WAVE];
#pragma unroll
  for (int r = 0; r < ROWS_PER_WAVE; ++r) {
    m[r] = -INFINITY;
    l[r] = 0.0f;
#pragma unroll
    for (int k = 0; k < 3; ++k) o[r][k] = make_float4(0.f, 0.f, 0.f, 0.f);
  }

  const float scale = 0.036084391824351615f;  // 1/sqrt(768)
  const int jmax = i0 + ROWS_PER_WAVE - 1;    // causal bound for the last row we own

  for (int j = 0; j <= jmax; ++j) {
    const float4* xj = (const float4*)(xb + (size_t)j * kD);
    float4 v0 = xj[lane];
    float4 v1 = xj[64 + lane];
    float4 v2 = xj[128 + lane];
    const float mj = mrow[j];
    const bool mok = (mj != 0.0f);

#pragma unroll
    for (int r = 0; r < ROWS_PER_WAVE; ++r) {
      // partial dot over this lane's 12 elements
      float d = v0.x * q[r][0].x + v0.y * q[r][0].y + v0.z * q[r][0].z + v0.w * q[r][0].w
              + v1.x * q[r][1].x + v1.y * q[r][1].y + v1.z * q[r][1].z + v1.w * q[r][1].w
              + v2.x * q[r][2].x + v2.y * q[r][2].y + v2.z * q[r][2].z + v2.w * q[r][2].w;
      // wave-wide reduction (64 lanes)
#pragma unroll
      for (int off = 32; off > 0; off >>= 1) d += __shfl_xor(d, off, 64);

      // causal predicate for this row; -inf contributes p=0, corr=1 (m finite after j=0)
      const float s = (j <= i0 + r) ? d * scale : -INFINITY;
      const float mn   = fmaxf(m[r], s);
      const float corr = __expf(m[r] - mn);   // j=0: exp(-inf)=0 zeroes stale state
      const float p    = __expf(s - mn);
      l[r] = l[r] * corr + p;
      const float w = mok ? p : 0.0f;         // post-softmax padding mask (numerator only)
#pragma unroll
      for (int k = 0; k < 3; ++k) {
        const float4 v = (k == 0) ? v0 : (k == 1) ? v1 : v2;
        o[r][k].x = o[r][k].x * corr + w * v.x;
        o[r][k].y = o[r][k].y * corr + w * v.y;
        o[r][k].z = o[r][k].z * corr + w * v.z;
        o[r][k].w = o[r][k].w * corr + w * v.w;
      }
      m[r] = mn;
    }
  }

  // Epilogue: divide by full-denominator l, gate by mask_i, write [attn | x_i]
#pragma unroll
  for (int r = 0; r < ROWS_PER_WAVE; ++r) {
    const float mi = mrow[i0 + r];
    const float invl = (mi != 0.0f) ? (1.0f / l[r]) : 0.0f;
    float* orow = out + (size_t)(rowBase + r) * (2 * kD);
    float4* oA = (float4*)orow;          // attention half
    float4* oS = (float4*)(orow + kD);   // self-hidden half
#pragma unroll
    for (int k = 0; k < 3; ++k) {
      float4 t;
      t.x = o[r][k].x * invl;
      t.y = o[r][k].y * invl;
      t.z = o[r][k].z * invl;
      t.w = o[r][k].w * invl;
      oA[k * 64 + lane] = t;
      oS[k * 64 + lane] = q[r][k];
    }
  }
}

extern "C" void kernel_launch(void* const* d_in, const int* in_sizes, int n_in,
                              void* d_out, int out_size, void* d_ws, size_t ws_size,
                              hipStream_t stream) {
  const float* x    = (const float*)d_in[0];  // text_inputs [B,T,D]
  const float* mask = (const float*)d_in[1];  // sit_mask    [B,T]
  // d_in[2] = proposition_matrix — unused by the reference computation
  float* out = (float*)d_out;                 // [B,T,2D] fp32

  dim3 grid(kB * kT / ROWS_PER_BLOCK);        // 1024 blocks
  dim3 block(WAVES_PER_BLOCK * 64);           // 256 threads
  attn_fused<<<grid, block, 0, stream>>>(x, mask, out);
}

// Round 2
// 577.640 us; speedup vs baseline: 10.0129x; 10.0129x over previous
//
#include <hip/hip_runtime.h>
#include <math.h>

// B=8, T=2048, D=768. out[b,i,:768] = masked-softmax attention, out[b,i,768:] = x[b,i].
// Softmax denominator over ALL causal j (mask applied after softmax, numerator only).
constexpr int kT = 2048;
constexpr int kD = 768;
constexpr int Bq = 32;   // Q rows per workgroup
constexpr int Bk = 16;   // KV rows per tile

typedef __attribute__((ext_vector_type(8))) short short8;
typedef __attribute__((ext_vector_type(4))) float f32x4;
typedef __attribute__((ext_vector_type(16))) float f32x16;

__device__ __forceinline__ unsigned bf16bits(float f) {
  unsigned u = __builtin_bit_cast(unsigned, f);
  u += 0x7fffu + ((u >> 16) & 1u);   // round-to-nearest-even
  return u >> 16;
}

__global__ __launch_bounds__(256, 2) void attn_mfma(
    const float* __restrict__ x, const float* __restrict__ mask,
    float* __restrict__ out)
{
  const int tid = threadIdx.x;
  const int w   = tid >> 6;          // wave 0..3 (owns D-chunk [192w,192w+192))
  const int l   = tid & 63;
  const int l15 = l & 15, q4 = l >> 4;   // 16x16 frag roles
  const int l31 = l & 31, h2 = l >> 5;   // 32x32 frag roles

  // heavy Q-tiles (large i0) first for load balance
  const int qt = 511 - (int)blockIdx.x;
  const int b  = qt >> 6;
  const int i0 = (qt & 63) << 5;

  const float* xb   = x + (size_t)b * kT * kD;
  const float* mrow = mask + (size_t)b * kT;

  __shared__ unsigned short xK[Bk][776];   // bf16 KV tile, padded stride (b128-conflict-free)
  __shared__ float sPart[4][Bq][Bk];       // per-wave partial scores
  __shared__ unsigned short Pm[Bq][Bk];    // masked softmax numerators, bf16
  __shared__ float corrS[Bq];
  __shared__ float invlS[Bq];

  // ---- cache Q fragments (bf16) for this wave's D-chunk: a-frag A[m=l15][k=8*q4+e] ----
  short8 qf[2][6];
#pragma unroll
  for (int mt = 0; mt < 2; ++mt) {
    const int row = i0 + 16 * mt + l15;
#pragma unroll
    for (int s = 0; s < 6; ++s) {
      const float* p = xb + (size_t)row * kD + 192 * w + 32 * s + 8 * q4;
      float4 f0 = *(const float4*)p;
      float4 f1 = *(const float4*)(p + 4);
      short8 a;
      a[0] = (short)bf16bits(f0.x); a[1] = (short)bf16bits(f0.y);
      a[2] = (short)bf16bits(f0.z); a[3] = (short)bf16bits(f0.w);
      a[4] = (short)bf16bits(f1.x); a[5] = (short)bf16bits(f1.y);
      a[6] = (short)bf16bits(f1.z); a[7] = (short)bf16bits(f1.w);
      qf[mt][s] = a;
    }
  }

  f32x16 o[6];
#pragma unroll
  for (int nt = 0; nt < 6; ++nt)
#pragma unroll
    for (int e = 0; e < 16; ++e) o[nt][e] = 0.0f;

  float mrun = -INFINITY, lrun = 0.0f;
  const float scale = 0.036084391824351615f;  // 1/sqrt(768)
  const int nTiles = i0 / Bk + 2;

  const int sr = tid >> 3;        // softmax row 0..31 (8 threads/row)
  const int sj = (tid & 7) * 2;   // this thread's j pair within tile
  const int srow_i = i0 + sr;

  for (int t = 0; t < nTiles; ++t) {
    const int j0 = t * Bk;
    __syncthreads();  // prev PV finished reading xK

    // ---- stage x[j0..j0+16) -> xK bf16 (coalesced float4 reads) ----
    {
      const int jj = tid >> 4;
      const int c0 = tid & 15;
      const float* src = xb + (size_t)(j0 + jj) * kD;
#pragma unroll
      for (int it = 0; it < 12; ++it) {
        const int d4 = c0 + 16 * it;
        float4 f = *(const float4*)(src + 4 * d4);
        uint2 wv;
        wv.x = bf16bits(f.x) | (bf16bits(f.y) << 16);
        wv.y = bf16bits(f.z) | (bf16bits(f.w) << 16);
        *(uint2*)&xK[jj][4 * d4] = wv;
      }
    }
    __syncthreads();  // xK ready

    // ---- QK^T partial over this wave's 192-d chunk ----
    {
      f32x4 sf[2];
#pragma unroll
      for (int mt = 0; mt < 2; ++mt)
#pragma unroll
        for (int e = 0; e < 4; ++e) sf[mt][e] = 0.0f;
#pragma unroll
      for (int s = 0; s < 6; ++s) {
        short8 kb = *(const short8*)&xK[l15][192 * w + 32 * s + 8 * q4];
#pragma unroll
        for (int mt = 0; mt < 2; ++mt)
          sf[mt] = __builtin_amdgcn_mfma_f32_16x16x32_bf16(qf[mt][s], kb, sf[mt], 0, 0, 0);
      }
#pragma unroll
      for (int mt = 0; mt < 2; ++mt)
#pragma unroll
        for (int e = 0; e < 4; ++e)
          sPart[w][16 * mt + 4 * q4 + e][l15] = sf[mt][e];
    }
    __syncthreads();  // sPart ready

    // ---- online softmax (8 threads per row; state replicated in-lane) ----
    {
      float s0 = 0.f, s1 = 0.f;
#pragma unroll
      for (int ww = 0; ww < 4; ++ww) { s0 += sPart[ww][sr][sj]; s1 += sPart[ww][sr][sj + 1]; }
      const int ja = j0 + sj, jb = j0 + sj + 1;
      float a0 = (ja <= srow_i) ? s0 * scale : -INFINITY;
      float a1 = (jb <= srow_i) ? s1 * scale : -INFINITY;
      float loc = fmaxf(a0, a1);
      loc = fmaxf(loc, __shfl_xor(loc, 1, 64));
      loc = fmaxf(loc, __shfl_xor(loc, 2, 64));
      loc = fmaxf(loc, __shfl_xor(loc, 4, 64));
      const float mn   = fmaxf(mrun, loc);     // finite from tile 0 (j=0<=i always)
      const float corr = __expf(mrun - mn);    // tile 0: exp(-inf)=0
      const float p0 = __expf(a0 - mn);
      const float p1 = __expf(a1 - mn);
      float rs = p0 + p1;
      rs += __shfl_xor(rs, 1, 64);
      rs += __shfl_xor(rs, 2, 64);
      rs += __shfl_xor(rs, 4, 64);
      lrun = lrun * corr + rs;                 // denominator: UNMASKED p
      mrun = mn;
      const float w0 = (mrow[ja] != 0.f) ? p0 : 0.f;  // numerator: masked
      const float w1 = (mrow[jb] != 0.f) ? p1 : 0.f;
      *(unsigned*)&Pm[sr][sj] = bf16bits(w0) | (bf16bits(w1) << 16);
      if ((tid & 7) == 0) corrS[sr] = corr;
    }
    __syncthreads();  // Pm, corrS ready

    // ---- PV: O += P·V  (32x32x16, K = full tile) ----
    {
      float cr[16];
      bool need = false;
#pragma unroll
      for (int e = 0; e < 16; ++e) {
        cr[e] = corrS[(e & 3) + 8 * (e >> 2) + 4 * h2];
        need |= (cr[e] != 1.0f);
      }
      if (__any(need)) {
#pragma unroll
        for (int nt = 0; nt < 6; ++nt)
#pragma unroll
          for (int e = 0; e < 16; ++e) o[nt][e] *= cr[e];
      }
      short8 pa = *(const short8*)&Pm[l31][8 * h2];  // A[m=l31][k=8*h2+e]
#pragma unroll
      for (int nt = 0; nt < 6; ++nt) {
        const int dloc = 192 * w + 32 * nt + l31;
        short8 vb;
#pragma unroll
        for (int e = 0; e < 8; ++e) vb[e] = (short)xK[8 * h2 + e][dloc];  // B[k][n=l31]
        o[nt] = __builtin_amdgcn_mfma_f32_32x32x16_bf16(pa, vb, o[nt], 0, 0, 0);
      }
    }
  }

  // ---- epilogue ----
  if ((tid & 7) == 0) {
    const float mi = mrow[srow_i];
    invlS[sr] = (mi != 0.f) ? 1.0f / lrun : 0.0f;   // gate row by mask_i
  }
  __syncthreads();
  {
    float il[16];
#pragma unroll
    for (int e = 0; e < 16; ++e) il[e] = invlS[(e & 3) + 8 * (e >> 2) + 4 * h2];
    float* ob = out + (size_t)(b * kT + i0) * (2 * kD);
#pragma unroll
    for (int nt = 0; nt < 6; ++nt) {
      const int col = 192 * w + 32 * nt + l31;
#pragma unroll
      for (int e = 0; e < 16; ++e) {
        const int row = (e & 3) + 8 * (e >> 2) + 4 * h2;  // verified 32x32 C/D layout
        ob[(size_t)row * (2 * kD) + col] = o[nt][e] * il[e];
      }
    }
    // self-hidden half: exact fp32 copy of x
#pragma unroll
    for (int pass = 0; pass < 2; ++pass) {
      const int rr = (tid >> 4) + 16 * pass;
      const float* srcr = xb + (size_t)(i0 + rr) * kD;
      float* dstr = ob + (size_t)rr * (2 * kD) + kD;
#pragma unroll
      for (int it = 0; it < 12; ++it) {
        const int d4 = (tid & 15) + 16 * it;
        *(float4*)(dstr + 4 * d4) = *(const float4*)(srcr + 4 * d4);
      }
    }
  }
}

extern "C" void kernel_launch(void* const* d_in, const int* in_sizes, int n_in,
                              void* d_out, int out_size, void* d_ws, size_t ws_size,
                              hipStream_t stream) {
  const float* x    = (const float*)d_in[0];
  const float* mask = (const float*)d_in[1];
  float* out = (float*)d_out;
  attn_mfma<<<dim3(512), dim3(256), 0, stream>>>(x, mask, out);
}

// Round 3
// 500.470 us; speedup vs baseline: 11.5569x; 1.1542x over previous
//
#include <hip/hip_runtime.h>
#include <math.h>

// B=8, T=2048, D=768. out[b,i,:768] = masked softmax attn (denominator over ALL
// causal j; sit-mask zeroes numerator only; row gated by mask_i), out[b,i,768:] = x[b,i].
constexpr int kT = 2048;
constexpr int kD = 768;

typedef __attribute__((ext_vector_type(8))) short short8;
typedef __attribute__((ext_vector_type(4))) float f32x4;
typedef __attribute__((ext_vector_type(16))) float f32x16;

#define FB(f) __builtin_bit_cast(unsigned, (f))
// (hi[31:16]<<16) | lo[31:16]  — bf16 truncation pack, 1 v_perm
__device__ __forceinline__ unsigned pk_hi16(unsigned hi, unsigned lo) {
  return __builtin_amdgcn_perm(hi, lo, 0x07060302);
}
// (hi[15:0]<<16) | lo[15:0]
__device__ __forceinline__ unsigned pk_lo16(unsigned hi, unsigned lo) {
  return __builtin_amdgcn_perm(hi, lo, 0x05040100);
}

__global__ __launch_bounds__(256, 2) void attn_mfma2(
    const float* __restrict__ x, const float* __restrict__ mask,
    float* __restrict__ out)
{
  const int tid = threadIdx.x;
  const int w = tid >> 6, l = tid & 63;
  const int l15 = l & 15, q4 = l >> 4;   // 16x16 roles; also staging (col,rowgrp)
  const int l31 = l & 31, h2 = l >> 5;   // 32x32 roles

  // pair blocks so each CU slot gets qt + (511-qt) -> equal total tiles
  const int bid = (int)blockIdx.x;
  const int qt = (bid < 256) ? (2 * bid) : (511 - 2 * (bid - 256));
  const int b = qt >> 6;
  const int i0 = (qt & 63) << 5;         // this block: Q rows i0..i0+31

  const float* xb = x + (size_t)b * kT * kD;
  const float* mrow = mask + (size_t)b * kT;

  __shared__ unsigned short xK[16][776];      // row-major KV tile (QK^T B-frags)
  __shared__ unsigned short VTb[192 * 64];    // blocked-transposed V (PV B-frags)
  __shared__ float sPart[4][16][36];          // per-wave partial S, [w][j][i], pad 36
  __shared__ unsigned short Pm[32][16];       // masked P (bf16), cols in jstore order
  __shared__ float corrS[32];
  __shared__ float invlS[32];

  // ---- Q fragments for this wave's 192-d chunk: A[m=l15][k=8*q4+e] ----
  short8 qf[2][6];
#pragma unroll
  for (int mt = 0; mt < 2; ++mt) {
    const int row = i0 + 16 * mt + l15;
#pragma unroll
    for (int s = 0; s < 6; ++s) {
      const float* p = xb + (size_t)row * kD + 192 * w + 32 * s + 8 * q4;
      float4 f0 = *(const float4*)p;
      float4 f1 = *(const float4*)(p + 4);
      uint4 u;
      u.x = pk_hi16(FB(f0.y), FB(f0.x));
      u.y = pk_hi16(FB(f0.w), FB(f0.z));
      u.z = pk_hi16(FB(f1.y), FB(f1.x));
      u.w = pk_hi16(FB(f1.w), FB(f1.z));
      qf[mt][s] = __builtin_bit_cast(short8, u);
    }
  }

  f32x16 o[6];
#pragma unroll
  for (int nt = 0; nt < 6; ++nt)
#pragma unroll
    for (int e = 0; e < 16; ++e) o[nt][e] = 0.0f;

  float mrun = -INFINITY, lrun = 0.0f;
  const float scale = 0.036084391824351615f;  // 1/sqrt(768)
  const int nTiles = i0 / 16 + 2;

  // softmax roles: 8 threads per row; jstore pair (2q,2q+1) <-> actual j {jA, jA+4}
  const int q = tid & 7, sr = tid >> 3;
  const int jA = (q >> 1) + 8 * (q & 1);
  const int irow = i0 + sr;

  // PV B-frag base offset into VTb (invariant over nt; +512 per nt)
  const int D0 = 48 * w + (l31 >> 2);
  const int vtb_off0 = D0 * 64 + (((l31 & 3) ^ (D0 & 3)) << 4)
                     + ((8 * h2) ^ (8 * ((l31 >> 4) & 1)));

  // ---- prefetch tile 0 ----
  float4 pf[3][4];
#pragma unroll
  for (int it = 0; it < 3; ++it)
#pragma unroll
    for (int jj = 0; jj < 4; ++jj)
      pf[it][jj] = *(const float4*)(xb + (size_t)(q4 + 4 * jj) * kD
                                    + 4 * (l15 + 16 * it + 48 * w));

  for (int t = 0; t < nTiles; ++t) {
    const int j0 = t * 16;
    __syncthreads();  // prev PV done reading xK/VTb

    // ---- stage pf -> xK (row-major) + VTb (blocked transpose), bf16 ----
#pragma unroll
    for (int it = 0; it < 3; ++it) {
      const int d4 = l15 + 16 * it + 48 * w;
      unsigned lo[4], hi[4];
#pragma unroll
      for (int jj = 0; jj < 4; ++jj) {
        lo[jj] = pk_hi16(FB(pf[it][jj].y), FB(pf[it][jj].x));
        hi[jj] = pk_hi16(FB(pf[it][jj].w), FB(pf[it][jj].z));
      }
#pragma unroll
      for (int jj = 0; jj < 4; ++jj) {
        uint2 v; v.x = lo[jj]; v.y = hi[jj];
        *(uint2*)&xK[q4 + 4 * jj][4 * d4] = v;   // row = actual j (q4+4jj)
      }
      // VTb: content V[perm(js)][d] at [D][c^(D&3)][js ^ 8*((D>>2)&1)], js base 4*q4
      const int D = d4;
      const int jb = (4 * q4) ^ (8 * ((D >> 2) & 1));
      const int base = D * 64 + jb;
      uint2 v;
      v.x = pk_lo16(lo[1], lo[0]); v.y = pk_lo16(lo[3], lo[2]);
      *(uint2*)&VTb[base + (((0 ^ (D & 3))) << 4)] = v;
      v.x = pk_hi16(lo[1], lo[0]); v.y = pk_hi16(lo[3], lo[2]);
      *(uint2*)&VTb[base + (((1 ^ (D & 3))) << 4)] = v;
      v.x = pk_lo16(hi[1], hi[0]); v.y = pk_lo16(hi[3], hi[2]);
      *(uint2*)&VTb[base + (((2 ^ (D & 3))) << 4)] = v;
      v.x = pk_hi16(hi[1], hi[0]); v.y = pk_hi16(hi[3], hi[2]);
      *(uint2*)&VTb[base + (((3 ^ (D & 3))) << 4)] = v;
    }

    // ---- prefetch next tile (overlaps QK^T/softmax/PV) ----
    if (t + 1 < nTiles) {
      const int jn = j0 + 16;
#pragma unroll
      for (int it = 0; it < 3; ++it)
#pragma unroll
        for (int jj = 0; jj < 4; ++jj)
          pf[it][jj] = *(const float4*)(xb + (size_t)(jn + q4 + 4 * jj) * kD
                                        + 4 * (l15 + 16 * it + 48 * w));
    }
    __syncthreads();  // xK/VTb ready

    // ---- QK^T partial over this wave's 192-d chunk ----
    {
      f32x4 sf0, sf1;
#pragma unroll
      for (int e = 0; e < 4; ++e) { sf0[e] = 0.f; sf1[e] = 0.f; }
#pragma unroll
      for (int s = 0; s < 6; ++s) {
        short8 kb = *(const short8*)&xK[l15][192 * w + 32 * s + 8 * q4];
        sf0 = __builtin_amdgcn_mfma_f32_16x16x32_bf16(qf[0][s], kb, sf0, 0, 0, 0);
        sf1 = __builtin_amdgcn_mfma_f32_16x16x32_bf16(qf[1][s], kb, sf1, 0, 0, 0);
      }
      *(f32x4*)&sPart[w][l15][4 * q4]      = sf0;  // [w][j=l15][i-col]
      *(f32x4*)&sPart[w][l15][16 + 4 * q4] = sf1;
    }
    __syncthreads();

    // ---- online softmax (8 thr/row; this thread: actual j = jA, jA+4) ----
    {
      float s0 = 0.f, s1 = 0.f;
#pragma unroll
      for (int ww = 0; ww < 4; ++ww) {
        s0 += sPart[ww][jA][sr];
        s1 += sPart[ww][jA + 4][sr];
      }
      const int ja = j0 + jA, jb_ = j0 + jA + 4;
      float a0 = (ja  <= irow) ? s0 * scale : -INFINITY;
      float a1 = (jb_ <= irow) ? s1 * scale : -INFINITY;
      float loc = fmaxf(a0, a1);
      loc = fmaxf(loc, __shfl_xor(loc, 1, 64));
      loc = fmaxf(loc, __shfl_xor(loc, 2, 64));
      loc = fmaxf(loc, __shfl_xor(loc, 4, 64));
      const float mn = fmaxf(mrun, loc);
      const float corr = __expf(mrun - mn);   // tile 0: exp(-inf)=0
      const float p0 = __expf(a0 - mn);
      const float p1 = __expf(a1 - mn);
      float rs = p0 + p1;
      rs += __shfl_xor(rs, 1, 64);
      rs += __shfl_xor(rs, 2, 64);
      rs += __shfl_xor(rs, 4, 64);
      lrun = lrun * corr + rs;                // denominator: unmasked
      mrun = mn;
      const float w0 = (mrow[ja]  != 0.f) ? p0 : 0.f;  // numerator: masked
      const float w1 = (mrow[jb_] != 0.f) ? p1 : 0.f;
      *(unsigned*)&Pm[sr][2 * q] = pk_hi16(FB(w1), FB(w0));  // jstore cols 2q,2q+1
      if (q == 0) corrS[sr] = corr;
    }
    __syncthreads();  // Pm/corrS ready

    // ---- PV: O += P·V  (32x32x16, k runs in jstore order on both operands) ----
    {
      float cr[16];
      bool need = false;
#pragma unroll
      for (int e4 = 0; e4 < 4; ++e4) {
        f32x4 qd = *(const f32x4*)&corrS[8 * e4 + 4 * h2];
#pragma unroll
        for (int ee = 0; ee < 4; ++ee) {
          cr[4 * e4 + ee] = qd[ee];
          need |= (qd[ee] != 1.0f);
        }
      }
      if (__any(need)) {
#pragma unroll
        for (int nt = 0; nt < 6; ++nt)
#pragma unroll
          for (int e = 0; e < 16; ++e) o[nt][e] *= cr[e];
      }
      short8 pa = *(const short8*)&Pm[l31][8 * h2];  // A[m=i=l31][k=js=8h2+e]
#pragma unroll
      for (int nt = 0; nt < 6; ++nt) {
        short8 vb = *(const short8*)&VTb[vtb_off0 + 512 * nt];  // B[k=js][n=d]
        o[nt] = __builtin_amdgcn_mfma_f32_32x32x16_bf16(pa, vb, o[nt], 0, 0, 0);
      }
    }
  }

  // ---- epilogue ----
  if (q == 0) invlS[sr] = (mrow[irow] != 0.f) ? 1.0f / lrun : 0.0f;
  __syncthreads();
  {
    float il[16];
#pragma unroll
    for (int e4 = 0; e4 < 4; ++e4) {
      f32x4 qd = *(const f32x4*)&invlS[8 * e4 + 4 * h2];
#pragma unroll
      for (int ee = 0; ee < 4; ++ee) il[4 * e4 + ee] = qd[ee];
    }
    float* ob = out + (size_t)(b * kT + i0) * (2 * kD);
#pragma unroll
    for (int nt = 0; nt < 6; ++nt) {
      const int col = 192 * w + 32 * nt + l31;
#pragma unroll
      for (int e = 0; e < 16; ++e) {
        const int row = (e & 3) + 8 * (e >> 2) + 4 * h2;  // verified 32x32 C/D layout
        ob[(size_t)row * (2 * kD) + col] = o[nt][e] * il[e];
      }
    }
    // self-hidden half: exact fp32 copy
#pragma unroll
    for (int pass = 0; pass < 2; ++pass) {
      const int rr = (tid >> 4) + 16 * pass;
      const float* srcr = xb + (size_t)(i0 + rr) * kD;
      float* dstr = ob + (size_t)rr * (2 * kD) + kD;
#pragma unroll
      for (int it = 0; it < 12; ++it) {
        const int d4 = (tid & 15) + 16 * it;
        *(float4*)(dstr + 4 * d4) = *(const float4*)(srcr + 4 * d4);
      }
    }
  }
}

extern "C" void kernel_launch(void* const* d_in, const int* in_sizes, int n_in,
                              void* d_out, int out_size, void* d_ws, size_t ws_size,
                              hipStream_t stream) {
  const float* x    = (const float*)d_in[0];
  const float* mask = (const float*)d_in[1];
  float* out = (float*)d_out;
  attn_mfma2<<<dim3(512), dim3(256), 0, stream>>>(x, mask, out);
}

// Round 4
// 487.461 us; speedup vs baseline: 11.8653x; 1.0267x over previous
//
#include <hip/hip_runtime.h>
#include <math.h>

// B=8, T=2048, D=768. out[b,i,:768] = masked softmax attn (denominator over ALL
// causal j; sit-mask zeroes numerator only; row gated by mask_i), out[b,i,768:] = x[b,i].
constexpr int kT = 2048;
constexpr int kD = 768;

typedef __attribute__((ext_vector_type(8))) short short8;
typedef __attribute__((ext_vector_type(4))) float f32x4;
typedef __attribute__((ext_vector_type(16))) float f32x16;

#define FB(f) __builtin_bit_cast(unsigned, (f))
__device__ __forceinline__ unsigned pk_hi16(unsigned hi, unsigned lo) {
  return __builtin_amdgcn_perm(hi, lo, 0x07060302);  // bf16 truncation pack
}
__device__ __forceinline__ unsigned pk_lo16(unsigned hi, unsigned lo) {
  return __builtin_amdgcn_perm(hi, lo, 0x05040100);
}

// Workgroup barrier WITHOUT the vmcnt(0) drain __syncthreads() emits.
// lgkmcnt(0) makes this wave's LDS writes visible; global loads stay in flight
// (consumers get compiler-inserted vmcnt waits at use). gfx9 waitcnt encoding:
// vmcnt[3:0]=0xF, expcnt=7<<4, lgkmcnt=0, vmcnt[5:4]=3<<14 -> 0xC07F.
__device__ __forceinline__ void lds_barrier() {
  asm volatile("" ::: "memory");
  __builtin_amdgcn_s_waitcnt(0xC07F);
  __builtin_amdgcn_s_barrier();
  asm volatile("" ::: "memory");
}

__global__ __launch_bounds__(256, 2) void attn_mfma3(
    const float* __restrict__ x, const float* __restrict__ mask,
    float* __restrict__ out)
{
  const int tid = threadIdx.x;
  const int w = tid >> 6, l = tid & 63;
  const int l15 = l & 15, q4 = l >> 4;   // 16x16 roles; also staging (col,rowgrp)
  const int l31 = l & 31, h2 = l >> 5;   // 32x32 roles

  // LPT order: heaviest Q-tiles (largest i0) dispatch first; batches interleaved.
  const int bid = (int)blockIdx.x;
  const int b  = bid & 7;
  const int i0 = (63 - (bid >> 3)) << 5;   // rows i0..i0+31

  const float* xb = x + (size_t)b * kT * kD;
  const float* mrow = mask + (size_t)b * kT;

  __shared__ unsigned short xK[16][776];      // row-major KV tile (QK^T B-frags)
  __shared__ unsigned short VTb[192 * 64];    // blocked-transposed V (PV B-frags)
  __shared__ float sPart[4][16][36];          // per-wave partial S, [w][j][i]
  __shared__ unsigned short Pm[32][16];       // masked P (bf16), jstore order
  __shared__ float corrS[32];
  __shared__ float invlS[32];

  // ---- Q fragments for this wave's 192-d chunk: A[m=l15][k=8*q4+e] ----
  short8 qf[2][6];
#pragma unroll
  for (int mt = 0; mt < 2; ++mt) {
    const int row = i0 + 16 * mt + l15;
#pragma unroll
    for (int s = 0; s < 6; ++s) {
      const float* p = xb + (size_t)row * kD + 192 * w + 32 * s + 8 * q4;
      float4 f0 = *(const float4*)p;
      float4 f1 = *(const float4*)(p + 4);
      uint4 u;
      u.x = pk_hi16(FB(f0.y), FB(f0.x));
      u.y = pk_hi16(FB(f0.w), FB(f0.z));
      u.z = pk_hi16(FB(f1.y), FB(f1.x));
      u.w = pk_hi16(FB(f1.w), FB(f1.z));
      qf[mt][s] = __builtin_bit_cast(short8, u);
    }
  }

  f32x16 o[6];
#pragma unroll
  for (int nt = 0; nt < 6; ++nt)
#pragma unroll
    for (int e = 0; e < 16; ++e) o[nt][e] = 0.0f;

  float mrun = -INFINITY, lrun = 0.0f;
  const float scale = 0.036084391824351615f;  // 1/sqrt(768)
  const int nTiles = i0 / 16 + 2;

  // softmax roles: 8 threads/row; jstore pair (2q,2q+1) <-> actual j {jA, jA+4}
  const int q = tid & 7, sr = tid >> 3;
  const int jA = (q >> 1) + 8 * (q & 1);
  const int irow = i0 + sr;

  // PV B-frag base offset into VTb (invariant over nt; +512 per nt)
  const int D0 = 48 * w + (l31 >> 2);
  const int vtb_off0 = D0 * 64 + (((l31 & 3) ^ (D0 & 3)) << 4)
                     + ((8 * h2) ^ (8 * ((l31 >> 4) & 1)));

  // ---- prefetch tile 0 ----
  float4 pf[3][4];
#pragma unroll
  for (int it = 0; it < 3; ++it)
#pragma unroll
    for (int jj = 0; jj < 4; ++jj)
      pf[it][jj] = *(const float4*)(xb + (size_t)(q4 + 4 * jj) * kD
                                    + 4 * (l15 + 16 * it + 48 * w));

  for (int t = 0; t < nTiles; ++t) {
    const int j0 = t * 16;
    // hoisted mask loads for this tile's softmax (issue early, use late)
    const float mskA = mrow[j0 + jA];
    const float mskB = mrow[j0 + jA + 4];

    lds_barrier();  // prev PV done reading xK/VTb (no vmcnt drain)

    // ---- stage pf -> xK (row-major) + VTb (blocked transpose), bf16 ----
#pragma unroll
    for (int it = 0; it < 3; ++it) {
      const int d4 = l15 + 16 * it + 48 * w;
      unsigned lo[4], hi[4];
#pragma unroll
      for (int jj = 0; jj < 4; ++jj) {
        lo[jj] = pk_hi16(FB(pf[it][jj].y), FB(pf[it][jj].x));
        hi[jj] = pk_hi16(FB(pf[it][jj].w), FB(pf[it][jj].z));
      }
#pragma unroll
      for (int jj = 0; jj < 4; ++jj) {
        uint2 v; v.x = lo[jj]; v.y = hi[jj];
        *(uint2*)&xK[q4 + 4 * jj][4 * d4] = v;   // row = actual j (q4+4jj)
      }
      const int D = d4;
      const int jb = (4 * q4) ^ (8 * ((D >> 2) & 1));
      const int base = D * 64 + jb;
      uint2 v;
      v.x = pk_lo16(lo[1], lo[0]); v.y = pk_lo16(lo[3], lo[2]);
      *(uint2*)&VTb[base + (((0 ^ (D & 3))) << 4)] = v;
      v.x = pk_hi16(lo[1], lo[0]); v.y = pk_hi16(lo[3], lo[2]);
      *(uint2*)&VTb[base + (((1 ^ (D & 3))) << 4)] = v;
      v.x = pk_lo16(hi[1], hi[0]); v.y = pk_lo16(hi[3], hi[2]);
      *(uint2*)&VTb[base + (((2 ^ (D & 3))) << 4)] = v;
      v.x = pk_hi16(hi[1], hi[0]); v.y = pk_hi16(hi[3], hi[2]);
      *(uint2*)&VTb[base + (((3 ^ (D & 3))) << 4)] = v;
    }

    // ---- prefetch next tile (stays in flight across the raw barriers) ----
    if (t + 1 < nTiles) {
      const int jn = j0 + 16;
#pragma unroll
      for (int it = 0; it < 3; ++it)
#pragma unroll
        for (int jj = 0; jj < 4; ++jj)
          pf[it][jj] = *(const float4*)(xb + (size_t)(jn + q4 + 4 * jj) * kD
                                        + 4 * (l15 + 16 * it + 48 * w));
    }
    lds_barrier();  // xK/VTb ready

    // ---- QK^T partial over this wave's 192-d chunk ----
    {
      f32x4 sf0, sf1;
#pragma unroll
      for (int e = 0; e < 4; ++e) { sf0[e] = 0.f; sf1[e] = 0.f; }
#pragma unroll
      for (int s = 0; s < 6; ++s) {
        short8 kb = *(const short8*)&xK[l15][192 * w + 32 * s + 8 * q4];
        sf0 = __builtin_amdgcn_mfma_f32_16x16x32_bf16(qf[0][s], kb, sf0, 0, 0, 0);
        sf1 = __builtin_amdgcn_mfma_f32_16x16x32_bf16(qf[1][s], kb, sf1, 0, 0, 0);
      }
      *(f32x4*)&sPart[w][l15][4 * q4]      = sf0;  // [w][j=l15][i-col]
      *(f32x4*)&sPart[w][l15][16 + 4 * q4] = sf1;
    }
    lds_barrier();  // sPart ready

    // ---- online softmax (8 thr/row; this thread: actual j = jA, jA+4) ----
    {
      float s0 = 0.f, s1 = 0.f;
#pragma unroll
      for (int ww = 0; ww < 4; ++ww) {
        s0 += sPart[ww][jA][sr];
        s1 += sPart[ww][jA + 4][sr];
      }
      const int ja = j0 + jA, jb_ = j0 + jA + 4;
      float a0 = (ja  <= irow) ? s0 * scale : -INFINITY;
      float a1 = (jb_ <= irow) ? s1 * scale : -INFINITY;
      float loc = fmaxf(a0, a1);
      loc = fmaxf(loc, __shfl_xor(loc, 1, 64));
      loc = fmaxf(loc, __shfl_xor(loc, 2, 64));
      loc = fmaxf(loc, __shfl_xor(loc, 4, 64));
      const float mn = fmaxf(mrun, loc);
      const float corr = __expf(mrun - mn);   // tile 0: exp(-inf)=0
      const float p0 = __expf(a0 - mn);
      const float p1 = __expf(a1 - mn);
      float rs = p0 + p1;
      rs += __shfl_xor(rs, 1, 64);
      rs += __shfl_xor(rs, 2, 64);
      rs += __shfl_xor(rs, 4, 64);
      lrun = lrun * corr + rs;                // denominator: unmasked
      mrun = mn;
      const float w0 = (mskA != 0.f) ? p0 : 0.f;  // numerator: masked
      const float w1 = (mskB != 0.f) ? p1 : 0.f;
      *(unsigned*)&Pm[sr][2 * q] = pk_hi16(FB(w1), FB(w0));  // jstore cols 2q,2q+1
      if (q == 0) corrS[sr] = corr;
    }
    lds_barrier();  // Pm/corrS ready

    // ---- PV: O += P·V  (32x32x16, k runs in jstore order on both operands) ----
    {
      float cr[16];
#pragma unroll
      for (int e4 = 0; e4 < 4; ++e4) {
        f32x4 qd = *(const f32x4*)&corrS[8 * e4 + 4 * h2];
#pragma unroll
        for (int ee = 0; ee < 4; ++ee) cr[4 * e4 + ee] = qd[ee];
      }
#pragma unroll
      for (int nt = 0; nt < 6; ++nt)
#pragma unroll
        for (int e = 0; e < 16; ++e) o[nt][e] *= cr[e];
      short8 pa = *(const short8*)&Pm[l31][8 * h2];  // A[m=i=l31][k=js=8h2+e]
#pragma unroll
      for (int nt = 0; nt < 6; ++nt) {
        short8 vb = *(const short8*)&VTb[vtb_off0 + 512 * nt];  // B[k=js][n=d]
        o[nt] = __builtin_amdgcn_mfma_f32_32x32x16_bf16(pa, vb, o[nt], 0, 0, 0);
      }
    }
  }

  // ---- epilogue ----
  if (q == 0) invlS[sr] = (mrow[irow] != 0.f) ? 1.0f / lrun : 0.0f;
  lds_barrier();
  {
    float il[16];
#pragma unroll
    for (int e4 = 0; e4 < 4; ++e4) {
      f32x4 qd = *(const f32x4*)&invlS[8 * e4 + 4 * h2];
#pragma unroll
      for (int ee = 0; ee < 4; ++ee) il[4 * e4 + ee] = qd[ee];
    }
    float* ob = out + (size_t)(b * kT + i0) * (2 * kD);
#pragma unroll
    for (int nt = 0; nt < 6; ++nt) {
      const int col = 192 * w + 32 * nt + l31;
#pragma unroll
      for (int e = 0; e < 16; ++e) {
        const int row = (e & 3) + 8 * (e >> 2) + 4 * h2;  // verified 32x32 C/D layout
        ob[(size_t)row * (2 * kD) + col] = o[nt][e] * il[e];
      }
    }
    // self-hidden half: exact fp32 copy
#pragma unroll
    for (int pass = 0; pass < 2; ++pass) {
      const int rr = (tid >> 4) + 16 * pass;
      const float* srcr = xb + (size_t)(i0 + rr) * kD;
      float* dstr = ob + (size_t)rr * (2 * kD) + kD;
#pragma unroll
      for (int it = 0; it < 12; ++it) {
        const int d4 = (tid & 15) + 16 * it;
        *(float4*)(dstr + 4 * d4) = *(const float4*)(srcr + 4 * d4);
      }
    }
  }
}

extern "C" void kernel_launch(void* const* d_in, const int* in_sizes, int n_in,
                              void* d_out, int out_size, void* d_ws, size_t ws_size,
                              hipStream_t stream) {
  const float* x    = (const float*)d_in[0];
  const float* mask = (const float*)d_in[1];
  float* out = (float*)d_out;
  attn_mfma3<<<dim3(512), dim3(256), 0, stream>>>(x, mask, out);
}